// Round 11
// baseline (76.302 us; speedup 1.0000x reference)
//
#include <hip/hip_runtime.h>

#define B_    64
#define N_    512
#define DIN_  256
#define DOUT_ 256
#define EPS_  1e-5f
#define ROWS_ (B_ * N_)   // 32768
#define NBLK_Y2 512

typedef __attribute__((ext_vector_type(8))) short bf16x8;   // 8 bf16 = 4 VGPRs
typedef __attribute__((ext_vector_type(8))) unsigned short u16x8;
typedef __attribute__((ext_vector_type(4))) float f32x4;
typedef __attribute__((ext_vector_type(4))) short short4v;

__device__ __forceinline__ short f2bf(float f) {
    unsigned u = __builtin_bit_cast(unsigned, f);
    u += 0x7fff + ((u >> 16) & 1);     // round-to-nearest-even
    return (short)(u >> 16);
}

// Fragment order: [kfrag][frag-row-group][lane(64)][8 shorts].
// Lane l of frag holds row/col = base + (l&15), k = kf*32 + (l>>4)*8 .. +8.

// WTf: W[k][e] -> fragment order.
__global__ __launch_bounds__(256) void wt_cvt(const float* __restrict__ W,
                                              short* __restrict__ WTf) {
    const int c = blockIdx.x * 256 + threadIdx.x;   // 0..8191
    const int kf = c >> 10, ef = (c >> 6) & 15, lp = c & 63;
    const int e = ef * 16 + (lp & 15);
    const int k0 = kf * 32 + (lp >> 4) * 8;
    bf16x8 h;
    #pragma unroll
    for (int j = 0; j < 8; ++j)
        h[j] = f2bf(W[(size_t)(k0 + j) * DOUT_ + e]);
    *(bf16x8*)&WTf[(size_t)c * 8] = h;
}

// adjf[bz][mt][kf16][mf4][64][8]: adj -> bf16 fragment order.
// Coalesced global read -> LDS (padded) -> gather -> coalesced global write.
// Removes the 16-row-scatter read that every prior gemm_y2 A-stage paid.
__global__ __launch_bounds__(512) void adj_cvt(const float* __restrict__ adj,
                                               short* __restrict__ adjf) {
    __shared__ short L[32 * 520];   // 32 rows x 512 k, +8 shorts pad (bank spread)
    const int tid = threadIdx.x;
    const int bid = blockIdx.x;
    const int swz = ((bid & 7) << 6) | (bid >> 3);   // same XCD map as gemm_y2f
    const int bz = swz >> 3, mt = swz & 7;
    const float* A = adj + (size_t)bz * N_ * N_ + (size_t)mt * 64 * N_;
    short* out = adjf + (size_t)(bz * 8 + mt) * 32768;

    #pragma unroll
    for (int h = 0; h < 2; ++h) {    // two 32-row halves (LDS 64KB limit)
        if (h) __syncthreads();      // protect LDS reuse
        const float* Ah = A + (size_t)h * 32 * N_;
        // read 32x512 f32 fully linear: 4096 float4, 8 per thread
        #pragma unroll
        for (int j = 0; j < 8; ++j) {
            int o = j * 512 + tid;                // float4 index
            int row = o >> 7, c4 = o & 127;
            float4 v = *(const float4*)&Ah[(size_t)row * N_ + c4 * 4];
            short4v s4 = { f2bf(v.x), f2bf(v.y), f2bf(v.z), f2bf(v.w) };
            *(short4v*)&L[row * 520 + c4 * 4] = s4;
        }
        __syncthreads();
        // gather to fragment order, write linear (1KB contiguous per wave)
        #pragma unroll
        for (int j = 0; j < 4; ++j) {
            int sh = j * 512 + tid;               // 0..2047 slot-in-half
            int kf = sh >> 7, mfh = (sh >> 6) & 1, lp = sh & 63;
            int rl = mfh * 16 + (lp & 15);
            int k  = kf * 32 + (lp >> 4) * 8;
            bf16x8 v = *(const bf16x8*)&L[rl * 520 + k];
            int s = kf * 256 + (h * 2 + mfh) * 64 + lp;
            *(bf16x8*)&out[(size_t)s * 8] = v;
        }
    }
}

// xw = x @ W, per-batch fragment order xwT[b][kf16][ef16][64][8].
// Writer-XCD aligned with gemm_y2f's readers. (R8 version, proven.)
__global__ __launch_bounds__(512, 4) void gemm_xw(const float* __restrict__ X,
                                                  const short* __restrict__ WTf,
                                                  short* __restrict__ xwT) {
    __shared__ __align__(16) short As[8 * 4 * 64 * 8];   // 32 KB
    const int tid = threadIdx.x, wv = tid >> 6, lane = tid & 63;
    const int lrow = lane & 15, lg = lane >> 4;
    const int bid = blockIdx.x;
    const int rt = ((bid & 7) * 8 + ((bid >> 3) & 7)) * 8 + (bid >> 6);
    const int rowBase = rt * 64;

    #pragma unroll
    for (int j = 0; j < 4; ++j) {
        int s = tid + j * 512;               // slot 0..2047
        int kf = s >> 8, mf = (s >> 6) & 3, lp = s & 63;
        int row = mf * 16 + (lp & 15);
        int k = kf * 32 + (lp >> 4) * 8;
        const float* src = &X[(size_t)(rowBase + row) * DIN_ + k];
        float4 v0 = *(const float4*)src;
        float4 v1 = *(const float4*)(src + 4);
        bf16x8 h = { f2bf(v0.x), f2bf(v0.y), f2bf(v0.z), f2bf(v0.w),
                     f2bf(v1.x), f2bf(v1.y), f2bf(v1.z), f2bf(v1.w) };
        *(bf16x8*)&As[s * 8] = h;
    }
    __syncthreads();

    const short* b0p = WTf + ((size_t)(wv * 2 + 0) * 64 + lane) * 8;
    const short* b1p = WTf + ((size_t)(wv * 2 + 1) * 64 + lane) * 8;
    bf16x8 bc0 = *(const bf16x8*)(b0p);
    bf16x8 bc1 = *(const bf16x8*)(b1p);
    f32x4 acc[4][2] = {};
    #pragma unroll 2
    for (int c = 0; c < 8; ++c) {
        const int cn = (c + 1 < 8) ? c + 1 : 7;
        bf16x8 bn0 = *(const bf16x8*)(b0p + cn * 8192);
        bf16x8 bn1 = *(const bf16x8*)(b1p + cn * 8192);
        const short* ab = &As[(c * 256 + lane) * 8];
        bf16x8 a0 = *(const bf16x8*)(ab);
        bf16x8 a1 = *(const bf16x8*)(ab + 512);
        bf16x8 a2 = *(const bf16x8*)(ab + 1024);
        bf16x8 a3 = *(const bf16x8*)(ab + 1536);
        acc[0][0] = __builtin_amdgcn_mfma_f32_16x16x32_bf16(a0, bc0, acc[0][0], 0, 0, 0);
        acc[0][1] = __builtin_amdgcn_mfma_f32_16x16x32_bf16(a0, bc1, acc[0][1], 0, 0, 0);
        acc[1][0] = __builtin_amdgcn_mfma_f32_16x16x32_bf16(a1, bc0, acc[1][0], 0, 0, 0);
        acc[1][1] = __builtin_amdgcn_mfma_f32_16x16x32_bf16(a1, bc1, acc[1][1], 0, 0, 0);
        acc[2][0] = __builtin_amdgcn_mfma_f32_16x16x32_bf16(a2, bc0, acc[2][0], 0, 0, 0);
        acc[2][1] = __builtin_amdgcn_mfma_f32_16x16x32_bf16(a2, bc1, acc[2][1], 0, 0, 0);
        acc[3][0] = __builtin_amdgcn_mfma_f32_16x16x32_bf16(a3, bc0, acc[3][0], 0, 0, 0);
        acc[3][1] = __builtin_amdgcn_mfma_f32_16x16x32_bf16(a3, bc1, acc[3][1], 0, 0, 0);
        bc0 = bn0; bc1 = bn1;
    }

    const int bz = rt >> 3, kfbase = (rt & 7) * 2;
    short* xwb = xwT + (size_t)bz * 131072;
    #pragma unroll
    for (int m = 0; m < 4; ++m)
        #pragma unroll
        for (int nf = 0; nf < 2; ++nf) {
            int kf = kfbase + (m >> 1);
            int ef = wv * 2 + nf;
            int lanep = lrow + 16 * ((m & 1) * 2 + (lg >> 1));
            size_t off = ((size_t)(kf * 16 + ef) * 64 + lanep) * 8 + (lg & 1) * 4;
            short4v o = { f2bf(acc[m][nf][0]), f2bf(acc[m][nf][1]),
                          f2bf(acc[m][nf][2]), f2bf(acc[m][nf][3]) };
            *(short4v*)&xwb[off] = o;
        }
}

// y2[b] = adj[b] @ xw[b] + bias, fused masked stats.
// LDS-FREE, barrier-free, all loads linear 1KB/wave: a-frags from adjf,
// b-frags from xwT (both XCD-local L2). 1-deep explicit double buffer.
template <bool BF16Y2>
__global__ __launch_bounds__(512, 2) void gemm_y2f(const short* __restrict__ adjf,
                                                   const short* __restrict__ xwT,
                                                   const float* __restrict__ bias,
                                                   const float* __restrict__ mask,
                                                   float* __restrict__ outf,
                                                   unsigned short* __restrict__ y2b,
                                                   float* __restrict__ psum,
                                                   float* __restrict__ psumsq,
                                                   float* __restrict__ pcnt) {
    const int tid = threadIdx.x, wv = tid >> 6, lane = tid & 63;
    const int lrow = lane & 15, lg = lane >> 4;
    const int bid = blockIdx.x;
    const int swz = ((bid & 7) << 6) | (bid >> 3);   // XCD-chunked
    const int bz = swz >> 3, mt = swz & 7;
    const int rowBase = mt * 64;
    const short* ab  = adjf + (size_t)(bz * 8 + mt) * 32768;
    const short* xwb = xwT + (size_t)bz * 131072;
    const short* b0p = xwb + ((size_t)(wv * 2 + 0) * 64 + lane) * 8;
    const short* b1p = xwb + ((size_t)(wv * 2 + 1) * 64 + lane) * 8;

    bf16x8 aP[2][4], bP[2][2];
    #pragma unroll
    for (int m = 0; m < 4; ++m)
        aP[0][m] = *(const bf16x8*)(ab + ((size_t)(0 * 4 + m) * 64 + lane) * 8);
    bP[0][0] = *(const bf16x8*)(b0p);
    bP[0][1] = *(const bf16x8*)(b1p);

    f32x4 acc[4][2] = {};
    #pragma unroll
    for (int kf = 0; kf < 16; ++kf) {        // fully unrolled: static buffer idx
        const int cur = kf & 1, nxt = cur ^ 1;
        if (kf < 15) {
            #pragma unroll
            for (int m = 0; m < 4; ++m)
                aP[nxt][m] = *(const bf16x8*)(ab + ((size_t)((kf + 1) * 4 + m) * 64 + lane) * 8);
            bP[nxt][0] = *(const bf16x8*)(b0p + (kf + 1) * 8192);
            bP[nxt][1] = *(const bf16x8*)(b1p + (kf + 1) * 8192);
        }
        #pragma unroll
        for (int m = 0; m < 4; ++m) {
            acc[m][0] = __builtin_amdgcn_mfma_f32_16x16x32_bf16(aP[cur][m], bP[cur][0], acc[m][0], 0, 0, 0);
            acc[m][1] = __builtin_amdgcn_mfma_f32_16x16x32_bf16(aP[cur][m], bP[cur][1], acc[m][1], 0, 0, 0);
        }
    }

    // ---- epilogue: bias + store + masked per-channel stats ----
    float* C = outf + (size_t)bz * N_ * DOUT_;
    unsigned short* Cb = y2b + (size_t)bz * N_ * DOUT_;
    float mv[4][4];
    #pragma unroll
    for (int m = 0; m < 4; ++m)
        #pragma unroll
        for (int r = 0; r < 4; ++r)
            mv[m][r] = mask[bz * N_ + rowBase + m * 16 + lg * 4 + r];
    float sv[2] = {0.f, 0.f}, sq[2] = {0.f, 0.f};
    #pragma unroll
    for (int nf = 0; nf < 2; ++nf) {
        const int col = wv * 32 + nf * 16 + lrow;
        const float bv = bias[col];
        #pragma unroll
        for (int m = 0; m < 4; ++m) {
            const int r0 = rowBase + m * 16 + lg * 4;
            #pragma unroll
            for (int r = 0; r < 4; ++r) {
                float v = acc[m][nf][r] + bv;
                if (BF16Y2)
                    Cb[(size_t)(r0 + r) * DOUT_ + col] = (unsigned short)f2bf(v);
                else
                    C[(size_t)(r0 + r) * DOUT_ + col] = v;
                float vm = v * mv[m][r];
                sv[nf] += vm;
                sq[nf] = fmaf(v, vm, sq[nf]);
            }
        }
    }
    #pragma unroll
    for (int nf = 0; nf < 2; ++nf) {
        sv[nf] += __shfl_xor(sv[nf], 16); sv[nf] += __shfl_xor(sv[nf], 32);
        sq[nf] += __shfl_xor(sq[nf], 16); sq[nf] += __shfl_xor(sq[nf], 32);
    }
    const int pidx = bz * 8 + mt;
    if (lg == 0) {
        #pragma unroll
        for (int nf = 0; nf < 2; ++nf) {
            psum[(size_t)pidx * DOUT_ + wv * 32 + nf * 16 + lrow]   = sv[nf];
            psumsq[(size_t)pidx * DOUT_ + wv * 32 + nf * 16 + lrow] = sq[nf];
        }
    }
    if (wv == 0) {
        float cnt = mask[bz * N_ + rowBase + lane];
        #pragma unroll
        for (int i = 1; i < 64; i <<= 1) cnt += __shfl_xor(cnt, i);
        if (lane == 0) pcnt[pidx] = cnt;
    }
}

// Fallback (ws too small for adjf): R8's in-kernel scatter-staged version.
__global__ __launch_bounds__(512, 4) void gemm_y2_stage(const float* __restrict__ adj,
                                                        const short* __restrict__ xwT,
                                                        const float* __restrict__ bias,
                                                        const float* __restrict__ mask,
                                                        unsigned short* __restrict__ y2b,
                                                        float* __restrict__ psum,
                                                        float* __restrict__ psumsq,
                                                        float* __restrict__ pcnt) {
    __shared__ __align__(16) short As[16 * 4 * 64 * 8];   // 64 KB
    const int tid = threadIdx.x, wv = tid >> 6, lane = tid & 63;
    const int lrow = lane & 15, lg = lane >> 4;
    const int bid = blockIdx.x;
    const int swz = ((bid & 7) << 6) | (bid >> 3);
    const int bz = swz >> 3, mt = swz & 7;
    const int rowBase = mt * 64;
    const float* A = adj + (size_t)bz * N_ * N_;
    const short* xwb = xwT + (size_t)bz * 131072;

    #pragma unroll
    for (int j = 0; j < 8; ++j) {
        int s = tid + j * 512;
        int kf = s >> 8, mf = (s >> 6) & 3, lp = s & 63;
        int row = mf * 16 + (lp & 15);
        int k = kf * 32 + (lp >> 4) * 8;
        const float* src = &A[(size_t)(rowBase + row) * N_ + k];
        float4 v0 = *(const float4*)src;
        float4 v1 = *(const float4*)(src + 4);
        bf16x8 h = { f2bf(v0.x), f2bf(v0.y), f2bf(v0.z), f2bf(v0.w),
                     f2bf(v1.x), f2bf(v1.y), f2bf(v1.z), f2bf(v1.w) };
        *(bf16x8*)&As[s * 8] = h;
    }
    __syncthreads();

    const short* b0p = xwb + ((size_t)(wv * 2 + 0) * 64 + lane) * 8;
    const short* b1p = xwb + ((size_t)(wv * 2 + 1) * 64 + lane) * 8;
    bf16x8 bpre[4][2];
    #pragma unroll
    for (int p = 0; p < 3; ++p) {
        bpre[p][0] = *(const bf16x8*)(b0p + p * 8192);
        bpre[p][1] = *(const bf16x8*)(b1p + p * 8192);
    }
    f32x4 acc[4][2] = {};
    #pragma unroll
    for (int c = 0; c < 16; ++c) {
        const int cn = (c + 3 < 16) ? c + 3 : 15;
        bpre[(c + 3) & 3][0] = *(const bf16x8*)(b0p + cn * 8192);
        bpre[(c + 3) & 3][1] = *(const bf16x8*)(b1p + cn * 8192);
        const short* abp = &As[(c * 256 + lane) * 8];
        bf16x8 a0 = *(const bf16x8*)(abp);
        bf16x8 a1 = *(const bf16x8*)(abp + 512);
        bf16x8 a2 = *(const bf16x8*)(abp + 1024);
        bf16x8 a3 = *(const bf16x8*)(abp + 1536);
        bf16x8 bc0 = bpre[c & 3][0];
        bf16x8 bc1 = bpre[c & 3][1];
        acc[0][0] = __builtin_amdgcn_mfma_f32_16x16x32_bf16(a0, bc0, acc[0][0], 0, 0, 0);
        acc[0][1] = __builtin_amdgcn_mfma_f32_16x16x32_bf16(a0, bc1, acc[0][1], 0, 0, 0);
        acc[1][0] = __builtin_amdgcn_mfma_f32_16x16x32_bf16(a1, bc0, acc[1][0], 0, 0, 0);
        acc[1][1] = __builtin_amdgcn_mfma_f32_16x16x32_bf16(a1, bc1, acc[1][1], 0, 0, 0);
        acc[2][0] = __builtin_amdgcn_mfma_f32_16x16x32_bf16(a2, bc0, acc[2][0], 0, 0, 0);
        acc[2][1] = __builtin_amdgcn_mfma_f32_16x16x32_bf16(a2, bc1, acc[2][1], 0, 0, 0);
        acc[3][0] = __builtin_amdgcn_mfma_f32_16x16x32_bf16(a3, bc0, acc[3][0], 0, 0, 0);
        acc[3][1] = __builtin_amdgcn_mfma_f32_16x16x32_bf16(a3, bc1, acc[3][1], 0, 0, 0);
    }

    unsigned short* Cb = y2b + (size_t)bz * N_ * DOUT_;
    float mv[4][4];
    #pragma unroll
    for (int m = 0; m < 4; ++m)
        #pragma unroll
        for (int r = 0; r < 4; ++r)
            mv[m][r] = mask[bz * N_ + rowBase + m * 16 + lg * 4 + r];
    float sv[2] = {0.f, 0.f}, sq[2] = {0.f, 0.f};
    #pragma unroll
    for (int nf = 0; nf < 2; ++nf) {
        const int col = wv * 32 + nf * 16 + lrow;
        const float bv = bias[col];
        #pragma unroll
        for (int m = 0; m < 4; ++m) {
            const int r0 = rowBase + m * 16 + lg * 4;
            #pragma unroll
            for (int r = 0; r < 4; ++r) {
                float v = acc[m][nf][r] + bv;
                Cb[(size_t)(r0 + r) * DOUT_ + col] = (unsigned short)f2bf(v);
                float vm = v * mv[m][r];
                sv[nf] += vm;
                sq[nf] = fmaf(v, vm, sq[nf]);
            }
        }
    }
    #pragma unroll
    for (int nf = 0; nf < 2; ++nf) {
        sv[nf] += __shfl_xor(sv[nf], 16); sv[nf] += __shfl_xor(sv[nf], 32);
        sq[nf] += __shfl_xor(sq[nf], 16); sq[nf] += __shfl_xor(sq[nf], 32);
    }
    const int pidx = bz * 8 + mt;
    if (lg == 0) {
        #pragma unroll
        for (int nf = 0; nf < 2; ++nf) {
            psum[(size_t)pidx * DOUT_ + wv * 32 + nf * 16 + lrow]   = sv[nf];
            psumsq[(size_t)pidx * DOUT_ + wv * 32 + nf * 16 + lrow] = sq[nf];
        }
    }
    if (wv == 0) {
        float cnt = mask[bz * N_ + rowBase + lane];
        #pragma unroll
        for (int i = 1; i < 64; i <<= 1) cnt += __shfl_xor(cnt, i);
        if (lane == 0) pcnt[pidx] = cnt;
    }
}

__global__ __launch_bounds__(256) void finalize2(const float* __restrict__ psum,
                                                 const float* __restrict__ psumsq,
                                                 const float* __restrict__ pcnt,
                                                 const float* __restrict__ gamma,
                                                 const float* __restrict__ beta,
                                                 float* __restrict__ scsh) {
    const int e = blockIdx.x, t = threadIdx.x;
    float s  = psum[(size_t)t * DOUT_ + e]   + psum[(size_t)(t + 256) * DOUT_ + e];
    float ss = psumsq[(size_t)t * DOUT_ + e] + psumsq[(size_t)(t + 256) * DOUT_ + e];
    float n  = pcnt[t] + pcnt[t + 256];
    #pragma unroll
    for (int i = 1; i < 64; i <<= 1) {
        s += __shfl_xor(s, i); ss += __shfl_xor(ss, i); n += __shfl_xor(n, i);
    }
    __shared__ float red[3][4];
    const int wv = t >> 6;
    if ((t & 63) == 0) { red[0][wv] = s; red[1][wv] = ss; red[2][wv] = n; }
    __syncthreads();
    if (t == 0) {
        s  = red[0][0] + red[0][1] + red[0][2] + red[0][3];
        ss = red[1][0] + red[1][1] + red[1][2] + red[1][3];
        n  = red[2][0] + red[2][1] + red[2][2] + red[2][3];
        float mean = s / n;
        float var = ss / n - mean * mean;
        float sc = rsqrtf(var + EPS_) * gamma[e];
        scsh[e] = sc;
        scsh[DOUT_ + e] = beta[e] - mean * sc;
    }
}

// out = relu((bf16(y2)*scale + shift) * mask), bf16 in -> f32 out
__global__ __launch_bounds__(256) void norm_relu_bf(const unsigned short* __restrict__ y2b,
                                                    const float* __restrict__ mask,
                                                    const float* __restrict__ scsh,
                                                    float* __restrict__ out) {
    const int nq = ROWS_ * (DOUT_ / 8);
    for (int q = blockIdx.x * blockDim.x + threadIdx.x; q < nq;
         q += gridDim.x * blockDim.x) {
        int e8 = (q & 31) * 8;
        int r = q >> 5;
        float m = mask[r];
        u16x8 uv = *(const u16x8*)&y2b[(size_t)q * 8];
        float4 sc0 = *(const float4*)&scsh[e8];
        float4 sc1 = *(const float4*)&scsh[e8 + 4];
        float4 sh0 = *(const float4*)&scsh[DOUT_ + e8];
        float4 sh1 = *(const float4*)&scsh[DOUT_ + e8 + 4];
        float4 o0, o1;
        #pragma unroll
        for (int j = 0; j < 4; ++j) {
            float f = __builtin_bit_cast(float, (unsigned)uv[j] << 16);
            (&o0.x)[j] = fmaxf(fmaf(f, (&sc0.x)[j], (&sh0.x)[j]) * m, 0.f);
        }
        #pragma unroll
        for (int j = 0; j < 4; ++j) {
            float f = __builtin_bit_cast(float, (unsigned)uv[j + 4] << 16);
            (&o1.x)[j] = fmaxf(fmaf(f, (&sc1.x)[j], (&sh1.x)[j]) * m, 0.f);
        }
        *(float4*)&out[(size_t)q * 8] = o0;
        *(float4*)&out[(size_t)q * 8 + 4] = o1;
    }
}

// f32 y2 in place (used when ws can't hold y2b)
__global__ __launch_bounds__(256) void norm_relu_f32(float* __restrict__ y2,
                                                     const float* __restrict__ mask,
                                                     const float* __restrict__ scsh) {
    const int nq = ROWS_ * (DOUT_ / 4);
    for (int q = blockIdx.x * blockDim.x + threadIdx.x; q < nq;
         q += gridDim.x * blockDim.x) {
        int e4 = (q & 63) * 4;
        int r = q >> 6;
        float m = mask[r];
        float4 v  = *(float4*)&y2[(size_t)q * 4];
        float4 sc = *(const float4*)&scsh[e4];
        float4 sh = *(const float4*)&scsh[DOUT_ + e4];
        v.x = fmaxf(fmaf(v.x, sc.x, sh.x) * m, 0.f);
        v.y = fmaxf(fmaf(v.y, sc.y, sh.y) * m, 0.f);
        v.z = fmaxf(fmaf(v.z, sc.z, sh.z) * m, 0.f);
        v.w = fmaxf(fmaf(v.w, sc.w, sh.w) * m, 0.f);
        *(float4*)&y2[(size_t)q * 4] = v;
    }
}

extern "C" void kernel_launch(void* const* d_in, const int* in_sizes, int n_in,
                              void* d_out, int out_size, void* d_ws, size_t ws_size,
                              hipStream_t stream) {
    const float* x      = (const float*)d_in[0];
    const float* adj    = (const float*)d_in[1];
    const float* mask   = (const float*)d_in[2];
    const float* weight = (const float*)d_in[3];
    const float* bias   = (const float*)d_in[4];
    const float* gamma  = (const float*)d_in[5];
    const float* beta   = (const float*)d_in[6];
    float* out = (float*)d_out;

    const size_t WTF_B   = 131072;
    const size_t XWT_B   = (size_t)DOUT_ * ROWS_ * 2;     // 16.8 MB
    const size_t ADJF_B  = (size_t)B_ * 8 * 32768 * 2;    // 33.5 MB
    const size_t STATS_B = (size_t)NBLK_Y2 * DOUT_ * 4 * 2 + NBLK_Y2 * 4 + 2048;
    const size_t Y2B_B   = (size_t)ROWS_ * DOUT_ * 2;     // 16.8 MB

    const bool has_adjf = ws_size >= WTF_B + XWT_B + ADJF_B + STATS_B;
    const bool has_y2b_new = ws_size >= WTF_B + XWT_B + ADJF_B + STATS_B + Y2B_B;

    char* p = (char*)d_ws;
    short* WTf = (short*)p;                 p += WTF_B;
    short* xwT = (short*)p;                 p += XWT_B;

    if (has_adjf) {
        short* adjf = (short*)p;            p += ADJF_B;
        float* psum = (float*)p;
        float* psumsq = psum + NBLK_Y2 * DOUT_;
        float* pcnt = psumsq + NBLK_Y2 * DOUT_;
        float* scsh = pcnt + NBLK_Y2;       p += STATS_B;
        unsigned short* y2b = (unsigned short*)p;

        wt_cvt<<<32, 256, 0, stream>>>(weight, WTf);
        adj_cvt<<<512, 512, 0, stream>>>(adj, adjf);
        gemm_xw<<<512, 512, 0, stream>>>(x, WTf, xwT);
        if (has_y2b_new) {
            gemm_y2f<true><<<NBLK_Y2, 512, 0, stream>>>(adjf, xwT, bias, mask, out,
                                                        y2b, psum, psumsq, pcnt);
            finalize2<<<256, 256, 0, stream>>>(psum, psumsq, pcnt, gamma, beta, scsh);
            norm_relu_bf<<<2048, 256, 0, stream>>>(y2b, mask, scsh, out);
        } else {
            gemm_y2f<false><<<NBLK_Y2, 512, 0, stream>>>(adjf, xwT, bias, mask, out,
                                                         (unsigned short*)out,
                                                         psum, psumsq, pcnt);
            finalize2<<<256, 256, 0, stream>>>(psum, psumsq, pcnt, gamma, beta, scsh);
            norm_relu_f32<<<2048, 256, 0, stream>>>(out, mask, scsh);
        }
    } else {
        // old layout: y2b right after xwT (fits in 34.8 MB, confirmed available)
        unsigned short* y2b = (unsigned short*)p;  p += Y2B_B;
        float* psum = (float*)p;
        float* psumsq = psum + NBLK_Y2 * DOUT_;
        float* pcnt = psumsq + NBLK_Y2 * DOUT_;
        float* scsh = pcnt + NBLK_Y2;

        wt_cvt<<<32, 256, 0, stream>>>(weight, WTf);
        gemm_xw<<<512, 512, 0, stream>>>(x, WTf, xwT);
        gemm_y2_stage<<<NBLK_Y2, 512, 0, stream>>>(adj, xwT, bias, mask, y2b,
                                                   psum, psumsq, pcnt);
        finalize2<<<256, 256, 0, stream>>>(psum, psumsq, pcnt, gamma, beta, scsh);
        norm_relu_bf<<<2048, 256, 0, stream>>>(y2b, mask, scsh, out);
    }
}

// Round 12
// 55.248 us; speedup vs baseline: 1.3811x; 1.3811x over previous
//
#include <hip/hip_runtime.h>

#define B_    64
#define N_    512
#define DIN_  256
#define DOUT_ 256
#define EPS_  1e-5f
#define ROWS_ (B_ * N_)   // 32768
#define NBLK_Y2 512

typedef __attribute__((ext_vector_type(8))) short bf16x8;   // 8 bf16 = 4 VGPRs
typedef __attribute__((ext_vector_type(8))) unsigned short u16x8;
typedef __attribute__((ext_vector_type(4))) float f32x4;
typedef __attribute__((ext_vector_type(4))) short short4v;

__device__ __forceinline__ short f2bf(float f) {
    unsigned u = __builtin_bit_cast(unsigned, f);
    u += 0x7fff + ((u >> 16) & 1);     // round-to-nearest-even
    return (short)(u >> 16);
}

// Fragment order: [kfrag][efrag/mfrag(16)][lane(64)][8 shorts].
// Lane l of frag (kf,*) holds row/col = base + (l&15), k = kf*32 + (l>>4)*8 .. +8.
// LDS slot swizzle: phys = s ^ ((s>>4)&3)  — makes the frag-scatter ds_writes
// spread across banks while keeping K-loop ds_read_b128 conflict-free.

// WTf: W[k][e] -> fragment order.
__global__ __launch_bounds__(256) void wt_cvt(const float* __restrict__ W,
                                              short* __restrict__ WTf) {
    const int c = blockIdx.x * 256 + threadIdx.x;   // 0..8191
    const int kf = c >> 10, ef = (c >> 6) & 15, lp = c & 63;
    const int e = ef * 16 + (lp & 15);
    const int k0 = kf * 32 + (lp >> 4) * 8;
    bf16x8 h;
    #pragma unroll
    for (int j = 0; j < 8; ++j)
        h[j] = f2bf(W[(size_t)(k0 + j) * DOUT_ + e]);
    *(bf16x8*)&WTf[(size_t)c * 8] = h;
}

// xw = x @ W, per-batch fragment order xwT[b][kf16][ef16][64][8].
// COALESCED A-staging: wave reads 1KB contiguous; scatter moved into LDS.
__global__ __launch_bounds__(512, 4) void gemm_xw(const float* __restrict__ X,
                                                  const short* __restrict__ WTf,
                                                  short* __restrict__ xwT) {
    __shared__ __align__(16) short As[8 * 4 * 64 * 8];   // 32 KB
    const int tid = threadIdx.x, wv = tid >> 6, lane = tid & 63;
    const int lrow = lane & 15, lg = lane >> 4;
    const int bid = blockIdx.x;
    const int rt = ((bid & 7) * 8 + ((bid >> 3) & 7)) * 8 + (bid >> 6);
    const int rowBase = rt * 64;

    // 64 rows x 256 k = 4096 float4, 8 per thread, fully linear global reads
    #pragma unroll
    for (int j = 0; j < 8; ++j) {
        int g = tid + j * 512;               // float4 index
        int row = g >> 6, c4 = g & 63;       // 64 float4 per row
        float4 v = *(const float4*)&X[(size_t)(rowBase + row) * DIN_ + c4 * 4];
        short4v s4 = { f2bf(v.x), f2bf(v.y), f2bf(v.z), f2bf(v.w) };
        int kf = c4 >> 3, sub = (c4 >> 1) & 3;
        int s = kf * 256 + (row >> 4) * 64 + (row & 15) + 16 * sub;
        int phys = s ^ sub;                  // = s ^ ((s>>4)&3)
        *(short4v*)&As[phys * 8 + (c4 & 1) * 4] = s4;
    }
    __syncthreads();

    const int lx = lane ^ (lg & 3);          // read-side swizzle (slot-level)
    const short* b0p = WTf + ((size_t)(wv * 2 + 0) * 64 + lane) * 8;
    const short* b1p = WTf + ((size_t)(wv * 2 + 1) * 64 + lane) * 8;
    bf16x8 bc0 = *(const bf16x8*)(b0p);
    bf16x8 bc1 = *(const bf16x8*)(b1p);
    f32x4 acc[4][2] = {};
    #pragma unroll 2
    for (int c = 0; c < 8; ++c) {
        const int cn = (c + 1 < 8) ? c + 1 : 7;
        bf16x8 bn0 = *(const bf16x8*)(b0p + cn * 8192);
        bf16x8 bn1 = *(const bf16x8*)(b1p + cn * 8192);
        const short* ab = &As[(c * 256 + lx) * 8];
        bf16x8 a0 = *(const bf16x8*)(ab);
        bf16x8 a1 = *(const bf16x8*)(ab + 512);
        bf16x8 a2 = *(const bf16x8*)(ab + 1024);
        bf16x8 a3 = *(const bf16x8*)(ab + 1536);
        acc[0][0] = __builtin_amdgcn_mfma_f32_16x16x32_bf16(a0, bc0, acc[0][0], 0, 0, 0);
        acc[0][1] = __builtin_amdgcn_mfma_f32_16x16x32_bf16(a0, bc1, acc[0][1], 0, 0, 0);
        acc[1][0] = __builtin_amdgcn_mfma_f32_16x16x32_bf16(a1, bc0, acc[1][0], 0, 0, 0);
        acc[1][1] = __builtin_amdgcn_mfma_f32_16x16x32_bf16(a1, bc1, acc[1][1], 0, 0, 0);
        acc[2][0] = __builtin_amdgcn_mfma_f32_16x16x32_bf16(a2, bc0, acc[2][0], 0, 0, 0);
        acc[2][1] = __builtin_amdgcn_mfma_f32_16x16x32_bf16(a2, bc1, acc[2][1], 0, 0, 0);
        acc[3][0] = __builtin_amdgcn_mfma_f32_16x16x32_bf16(a3, bc0, acc[3][0], 0, 0, 0);
        acc[3][1] = __builtin_amdgcn_mfma_f32_16x16x32_bf16(a3, bc1, acc[3][1], 0, 0, 0);
        bc0 = bn0; bc1 = bn1;
    }

    const int bz = rt >> 3, kfbase = (rt & 7) * 2;
    short* xwb = xwT + (size_t)bz * 131072;
    #pragma unroll
    for (int m = 0; m < 4; ++m)
        #pragma unroll
        for (int nf = 0; nf < 2; ++nf) {
            int kf = kfbase + (m >> 1);
            int ef = wv * 2 + nf;
            int lanep = lrow + 16 * ((m & 1) * 2 + (lg >> 1));
            size_t off = ((size_t)(kf * 16 + ef) * 64 + lanep) * 8 + (lg & 1) * 4;
            short4v o = { f2bf(acc[m][nf][0]), f2bf(acc[m][nf][1]),
                          f2bf(acc[m][nf][2]), f2bf(acc[m][nf][3]) };
            *(short4v*)&xwb[off] = o;
        }
}

// y2[b] = adj[b] @ xw[b] + bias, fused masked stats.
// COALESCED A-staging (was: 16-row scatter at 2KB stride — the suspected
// common bottleneck of R2-R11). Wave reads 1KB contiguous; LDS-side scatter
// with XOR swizzle. K-loop: 4-deep unrolled B register prefetch (R8).
__global__ __launch_bounds__(512, 4) void gemm_y2_stage(const float* __restrict__ adj,
                                                        const short* __restrict__ xwT,
                                                        const float* __restrict__ bias,
                                                        const float* __restrict__ mask,
                                                        unsigned short* __restrict__ y2b,
                                                        float* __restrict__ psum,
                                                        float* __restrict__ psumsq,
                                                        float* __restrict__ pcnt) {
    __shared__ __align__(16) short As[16 * 4 * 64 * 8];   // 64 KB
    const int tid = threadIdx.x, wv = tid >> 6, lane = tid & 63;
    const int lrow = lane & 15, lg = lane >> 4;
    const int bid = blockIdx.x;
    const int swz = ((bid & 7) << 6) | (bid >> 3);   // XCD-chunked
    const int bz = swz >> 3, mt = swz & 7;
    const int rowBase = mt * 64;
    const float* A = adj + (size_t)bz * N_ * N_;
    const short* xwb = xwT + (size_t)bz * 131072;

    // 64 rows x 512 k = 8192 float4, 16 per thread, fully linear global reads
    #pragma unroll
    for (int j = 0; j < 16; ++j) {
        int g = tid + j * 512;               // float4 index
        int row = g >> 7, c4 = g & 127;      // 128 float4 per row
        float4 v = *(const float4*)&A[(size_t)(rowBase + row) * N_ + c4 * 4];
        short4v s4 = { f2bf(v.x), f2bf(v.y), f2bf(v.z), f2bf(v.w) };
        int kf = c4 >> 3, sub = (c4 >> 1) & 3;
        int s = kf * 256 + (row >> 4) * 64 + (row & 15) + 16 * sub;
        int phys = s ^ sub;                  // = s ^ ((s>>4)&3)
        *(short4v*)&As[phys * 8 + (c4 & 1) * 4] = s4;
    }
    __syncthreads();

    const int lx = lane ^ (lg & 3);          // read-side swizzle
    const short* b0p = xwb + ((size_t)(wv * 2 + 0) * 64 + lane) * 8;
    const short* b1p = xwb + ((size_t)(wv * 2 + 1) * 64 + lane) * 8;
    bf16x8 bpre[4][2];
    #pragma unroll
    for (int p = 0; p < 3; ++p) {
        bpre[p][0] = *(const bf16x8*)(b0p + p * 8192);
        bpre[p][1] = *(const bf16x8*)(b1p + p * 8192);
    }
    f32x4 acc[4][2] = {};
    #pragma unroll
    for (int c = 0; c < 16; ++c) {           // fully unrolled: static bpre idx
        const int cn = (c + 3 < 16) ? c + 3 : 15;
        bpre[(c + 3) & 3][0] = *(const bf16x8*)(b0p + cn * 8192);
        bpre[(c + 3) & 3][1] = *(const bf16x8*)(b1p + cn * 8192);
        const short* abp = &As[(c * 256 + lx) * 8];
        bf16x8 a0 = *(const bf16x8*)(abp);
        bf16x8 a1 = *(const bf16x8*)(abp + 512);
        bf16x8 a2 = *(const bf16x8*)(abp + 1024);
        bf16x8 a3 = *(const bf16x8*)(abp + 1536);
        bf16x8 bc0 = bpre[c & 3][0];
        bf16x8 bc1 = bpre[c & 3][1];
        acc[0][0] = __builtin_amdgcn_mfma_f32_16x16x32_bf16(a0, bc0, acc[0][0], 0, 0, 0);
        acc[0][1] = __builtin_amdgcn_mfma_f32_16x16x32_bf16(a0, bc1, acc[0][1], 0, 0, 0);
        acc[1][0] = __builtin_amdgcn_mfma_f32_16x16x32_bf16(a1, bc0, acc[1][0], 0, 0, 0);
        acc[1][1] = __builtin_amdgcn_mfma_f32_16x16x32_bf16(a1, bc1, acc[1][1], 0, 0, 0);
        acc[2][0] = __builtin_amdgcn_mfma_f32_16x16x32_bf16(a2, bc0, acc[2][0], 0, 0, 0);
        acc[2][1] = __builtin_amdgcn_mfma_f32_16x16x32_bf16(a2, bc1, acc[2][1], 0, 0, 0);
        acc[3][0] = __builtin_amdgcn_mfma_f32_16x16x32_bf16(a3, bc0, acc[3][0], 0, 0, 0);
        acc[3][1] = __builtin_amdgcn_mfma_f32_16x16x32_bf16(a3, bc1, acc[3][1], 0, 0, 0);
    }

    // ---- epilogue: bias + bf16 store + masked per-channel stats ----
    unsigned short* Cb = y2b + (size_t)bz * N_ * DOUT_;
    float mv[4][4];
    #pragma unroll
    for (int m = 0; m < 4; ++m)
        #pragma unroll
        for (int r = 0; r < 4; ++r)
            mv[m][r] = mask[bz * N_ + rowBase + m * 16 + lg * 4 + r];
    float sv[2] = {0.f, 0.f}, sq[2] = {0.f, 0.f};
    #pragma unroll
    for (int nf = 0; nf < 2; ++nf) {
        const int col = wv * 32 + nf * 16 + lrow;
        const float bv = bias[col];
        #pragma unroll
        for (int m = 0; m < 4; ++m) {
            const int r0 = rowBase + m * 16 + lg * 4;
            #pragma unroll
            for (int r = 0; r < 4; ++r) {
                float v = acc[m][nf][r] + bv;
                Cb[(size_t)(r0 + r) * DOUT_ + col] = (unsigned short)f2bf(v);
                float vm = v * mv[m][r];
                sv[nf] += vm;
                sq[nf] = fmaf(v, vm, sq[nf]);
            }
        }
    }
    #pragma unroll
    for (int nf = 0; nf < 2; ++nf) {
        sv[nf] += __shfl_xor(sv[nf], 16); sv[nf] += __shfl_xor(sv[nf], 32);
        sq[nf] += __shfl_xor(sq[nf], 16); sq[nf] += __shfl_xor(sq[nf], 32);
    }
    const int pidx = bz * 8 + mt;
    if (lg == 0) {
        #pragma unroll
        for (int nf = 0; nf < 2; ++nf) {
            psum[(size_t)pidx * DOUT_ + wv * 32 + nf * 16 + lrow]   = sv[nf];
            psumsq[(size_t)pidx * DOUT_ + wv * 32 + nf * 16 + lrow] = sq[nf];
        }
    }
    if (wv == 0) {
        float cnt = mask[bz * N_ + rowBase + lane];
        #pragma unroll
        for (int i = 1; i < 64; i <<= 1) cnt += __shfl_xor(cnt, i);
        if (lane == 0) pcnt[pidx] = cnt;
    }
}

__global__ __launch_bounds__(256) void finalize2(const float* __restrict__ psum,
                                                 const float* __restrict__ psumsq,
                                                 const float* __restrict__ pcnt,
                                                 const float* __restrict__ gamma,
                                                 const float* __restrict__ beta,
                                                 float* __restrict__ scsh) {
    const int e = blockIdx.x, t = threadIdx.x;
    float s  = psum[(size_t)t * DOUT_ + e]   + psum[(size_t)(t + 256) * DOUT_ + e];
    float ss = psumsq[(size_t)t * DOUT_ + e] + psumsq[(size_t)(t + 256) * DOUT_ + e];
    float n  = pcnt[t] + pcnt[t + 256];
    #pragma unroll
    for (int i = 1; i < 64; i <<= 1) {
        s += __shfl_xor(s, i); ss += __shfl_xor(ss, i); n += __shfl_xor(n, i);
    }
    __shared__ float red[3][4];
    const int wv = t >> 6;
    if ((t & 63) == 0) { red[0][wv] = s; red[1][wv] = ss; red[2][wv] = n; }
    __syncthreads();
    if (t == 0) {
        s  = red[0][0] + red[0][1] + red[0][2] + red[0][3];
        ss = red[1][0] + red[1][1] + red[1][2] + red[1][3];
        n  = red[2][0] + red[2][1] + red[2][2] + red[2][3];
        float mean = s / n;
        float var = ss / n - mean * mean;
        float sc = rsqrtf(var + EPS_) * gamma[e];
        scsh[e] = sc;
        scsh[DOUT_ + e] = beta[e] - mean * sc;
    }
}

// out = relu((bf16(y2)*scale + shift) * mask), bf16 in -> f32 out
__global__ __launch_bounds__(256) void norm_relu_bf(const unsigned short* __restrict__ y2b,
                                                    const float* __restrict__ mask,
                                                    const float* __restrict__ scsh,
                                                    float* __restrict__ out) {
    const int nq = ROWS_ * (DOUT_ / 8);
    for (int q = blockIdx.x * blockDim.x + threadIdx.x; q < nq;
         q += gridDim.x * blockDim.x) {
        int e8 = (q & 31) * 8;
        int r = q >> 5;
        float m = mask[r];
        u16x8 uv = *(const u16x8*)&y2b[(size_t)q * 8];
        float4 sc0 = *(const float4*)&scsh[e8];
        float4 sc1 = *(const float4*)&scsh[e8 + 4];
        float4 sh0 = *(const float4*)&scsh[DOUT_ + e8];
        float4 sh1 = *(const float4*)&scsh[DOUT_ + e8 + 4];
        float4 o0, o1;
        #pragma unroll
        for (int j = 0; j < 4; ++j) {
            float f = __builtin_bit_cast(float, (unsigned)uv[j] << 16);
            (&o0.x)[j] = fmaxf(fmaf(f, (&sc0.x)[j], (&sh0.x)[j]) * m, 0.f);
        }
        #pragma unroll
        for (int j = 0; j < 4; ++j) {
            float f = __builtin_bit_cast(float, (unsigned)uv[j + 4] << 16);
            (&o1.x)[j] = fmaxf(fmaf(f, (&sc1.x)[j], (&sh1.x)[j]) * m, 0.f);
        }
        *(float4*)&out[(size_t)q * 8] = o0;
        *(float4*)&out[(size_t)q * 8 + 4] = o1;
    }
}

extern "C" void kernel_launch(void* const* d_in, const int* in_sizes, int n_in,
                              void* d_out, int out_size, void* d_ws, size_t ws_size,
                              hipStream_t stream) {
    const float* x      = (const float*)d_in[0];
    const float* adj    = (const float*)d_in[1];
    const float* mask   = (const float*)d_in[2];
    const float* weight = (const float*)d_in[3];
    const float* bias   = (const float*)d_in[4];
    const float* gamma  = (const float*)d_in[5];
    const float* beta   = (const float*)d_in[6];
    float* out = (float*)d_out;

    char* p = (char*)d_ws;
    short* WTf = (short*)p;                          p += 131072;
    short* xwT = (short*)p;                          p += (size_t)DOUT_ * ROWS_ * 2;
    unsigned short* y2b = (unsigned short*)p;        p += (size_t)ROWS_ * DOUT_ * 2;
    float* psum   = (float*)p;
    float* psumsq = psum + NBLK_Y2 * DOUT_;
    float* pcnt   = psumsq + NBLK_Y2 * DOUT_;
    float* scsh   = pcnt + NBLK_Y2;

    wt_cvt<<<32, 256, 0, stream>>>(weight, WTf);
    gemm_xw<<<512, 512, 0, stream>>>(x, WTf, xwT);
    gemm_y2_stage<<<NBLK_Y2, 512, 0, stream>>>(adj, xwT, bias, mask, y2b,
                                               psum, psumsq, pcnt);
    finalize2<<<256, 256, 0, stream>>>(psum, psumsq, pcnt, gamma, beta, scsh);
    norm_relu_bf<<<2048, 256, 0, stream>>>(y2b, mask, scsh, out);
}